// Round 7
// baseline (94.721 us; speedup 1.0000x reference)
//
#include <hip/hip_runtime.h>
#include <math.h>

#define NB 16384
typedef _Float16 f16;
typedef _Float16 f16x8 __attribute__((ext_vector_type(8)));
typedef _Float16 f16x4 __attribute__((ext_vector_type(4)));
typedef float f32x4 __attribute__((ext_vector_type(4)));

__device__ __forceinline__ float fast_sig(float v)  { return __builtin_amdgcn_rcpf(1.0f + __expf(-v)); }
__device__ __forceinline__ float fast_tanh(float v) { return 1.0f - 2.0f * __builtin_amdgcn_rcpf(1.0f + __expf(2.0f * v)); }

#define MFMA16(A, B, C) __builtin_amdgcn_mfma_f32_16x16x32_f16(A, B, C, 0, 0, 0)

// ---------------- kernel 1: es = mean_L(enc), BW-bound, high occupancy ----------
// 245760 float4 units (16384 rows x 15 quads); one thread per unit; 48 strided
// coalesced loads each. 960 blocks x 256 = 3840 waves = 15/CU -> latency hidden.
__global__ __launch_bounds__(256) void es_kernel(
    const float* __restrict__ enc, float* __restrict__ es)
{
    const int u = blockIdx.x * 256 + threadIdx.x;    // float4 unit
    const float4* e4 = (const float4*)enc;
    float ax = 0.f, ay = 0.f, az = 0.f, aw = 0.f;
    #pragma unroll 8
    for (int L = 0; L < 48; ++L) {
        const float4 v = e4[(size_t)L * (NB * 15) + u];
        ax += v.x; ay += v.y; az += v.z; aw += v.w;
    }
    const float s = 1.f / 48.f;
    float4 r; r.x = ax * s; r.y = ay * s; r.z = az * s; r.w = aw * s;
    ((float4*)es)[u] = r;
}

// ---------------- kernel 2: decode (round-6 verified structure) -----------------
// Per wave (= per block): 8 batch rows in a 16-row MFMA tile (rows 8-15 pad).
// Weights persistent in VGPRs as f16 B-fragments. Activations round-trip
// through two tiny LDS buffers for the D-layout -> A-layout transpose.
// x16 row layout (72 halves, 144B stride): [0..3]=rin [4..33]=enh [34..63]=h [64..71]=scratch
__global__ __launch_bounds__(64, 2) void decoder_kernel(
    const float* __restrict__ y,      // [B,13,4]
    const float* __restrict__ enc,    // [48,B,60]
    const float* __restrict__ esrc,   // [B,60] premeaned (or null -> fused scan)
    const float* __restrict__ hidden, // [B,30]
    const float* __restrict__ Wv,  const float* __restrict__ bv,
    const float* __restrict__ Wg,  const float* __restrict__ bg,
    const float* __restrict__ Wf1, const float* __restrict__ bf1,
    const float* __restrict__ Wf2, const float* __restrict__ bf2,
    const float* __restrict__ Wf3, const float* __restrict__ bf3,
    const float* __restrict__ Wih, const float* __restrict__ bih,
    const float* __restrict__ Whh, const float* __restrict__ bhh,
    float* __restrict__ out)          // [12,B]
{
    __shared__ __align__(16) f16 x16[16][72];
    __shared__ __align__(16) f16 z1b[16][32];

    const int l = threadIdx.x;
    const int r = l & 15, g = l >> 4;        // A-row / D-col = r; k-block & D-row-group = g
    const int bw = blockIdx.x * 8;           // wave's first global batch row
    const f32x4 kz = {0.f, 0.f, 0.f, 0.f};

    // ---- zero LDS
    #pragma unroll
    for (int d = 0; d < 9; ++d)  ((unsigned*)x16)[d * 64 + l] = 0u;
    #pragma unroll
    for (int d = 0; d < 4; ++d)  ((unsigned*)z1b)[d * 64 + l] = 0u;

    // ---- phase 1: es for this wave's 8 rows (read premeaned, or fused scan)
    float a0x=0,a0y=0,a0z=0,a0w=0, a1x=0,a1y=0,a1z=0,a1w=0;
    float esc;
    {
        const int u1 = 64 + l;
        if (esrc) {
            const float4* s4 = (const float4*)esrc;
            const size_t base = (size_t)bw * 15;
            const float4 v0 = s4[base + l];
            a0x = v0.x; a0y = v0.y; a0z = v0.z; a0w = v0.w;
            if (l < 56) {
                const float4 v1 = s4[base + u1];
                a1x = v1.x; a1y = v1.y; a1z = v1.z; a1w = v1.w;
            }
            esc = 1.f;
        } else {
            const float4* e4 = (const float4*)enc;
            const int u0r = l / 15, u0q = l - u0r * 15;
            const int u1r = u1 / 15, u1q = u1 - u1r * 15;
            const size_t o0 = (size_t)(bw + u0r) * 15 + u0q;
            const size_t o1 = (size_t)(bw + u1r) * 15 + u1q;
            #pragma unroll 4
            for (int L = 0; L < 48; ++L) {
                const size_t base = (size_t)L * (NB * 15);
                float4 v0 = e4[base + o0];
                a0x += v0.x; a0y += v0.y; a0z += v0.z; a0w += v0.w;
                if (l < 56) {
                    float4 v1 = e4[base + o1];
                    a1x += v1.x; a1y += v1.y; a1z += v1.z; a1w += v1.w;
                }
            }
            esc = 1.f / 48.f;
        }
    }

    // ---- load weight B-fragments (f16, persistent in VGPRs)
    // B-frag element e of lane l = W[k = kt*32 + g*8 + e][n = nt*16 + r]
    // (same (g,e)->k map used for A-frags => contraction is layout-invariant)
    f16x8 lf[2][8];                  // LSTM; t = gate*2 + jh; k: 0..33 Wih, 34..63 Whh
    #pragma unroll
    for (int kt = 0; kt < 2; ++kt)
        #pragma unroll
        for (int t = 0; t < 8; ++t) {
            const int gate = t >> 1, j = (t & 1) * 16 + r;
            const int trow = gate * 30 + j;
            f16x8 w;
            #pragma unroll
            for (int e = 0; e < 8; ++e) {
                const int k = kt * 32 + g * 8 + e;
                float val = 0.f;
                if (j < 30) val = (k < 34) ? Wih[trow * 34 + k] : Whh[trow * 30 + (k - 34)];
                w[e] = (f16)val;
            }
            lf[kt][t] = w;
        }
    f16x8 gf[2][2];                  // gate; kt0 over x16 cols 32..63 (kl>=2 -> h), kt1 over V
    #pragma unroll
    for (int nt = 0; nt < 2; ++nt) {
        const int j = nt * 16 + r;
        f16x8 w0, w1;
        #pragma unroll
        for (int e = 0; e < 8; ++e) {
            const int kl = g * 8 + e;
            w0[e] = (f16)((j < 30 && kl >= 2) ? Wg[j * 60 + (kl - 2)] : 0.f);
            w1[e] = (f16)((j < 30 && kl < 30) ? Wg[j * 60 + 30 + kl] : 0.f);
        }
        gf[0][nt] = w0; gf[1][nt] = w1;
    }
    f16x8 f1f[2];                    // fc1 over x16 cols 32..63 (kl>=2 -> h_new); se via bias
    #pragma unroll
    for (int nt = 0; nt < 2; ++nt) {
        const int j = nt * 16 + r;
        f16x8 w;
        #pragma unroll
        for (int e = 0; e < 8; ++e) {
            const int kl = g * 8 + e;
            w[e] = (f16)((j < 30 && kl >= 2) ? Wf1[j * 31 + (kl - 2)] : 0.f);
        }
        f1f[nt] = w;
    }
    f16x8 f2f;                       // fc2: z1(30) -> 15
    #pragma unroll
    for (int e = 0; e < 8; ++e) {
        const int kl = g * 8 + e;
        f2f[e] = (f16)((r < 15 && kl < 30) ? Wf2[r * 30 + kl] : 0.f);
    }
    f16x8 f3f;                       // fc3: z2(15) -> 1 (col 0 only)
    #pragma unroll
    for (int e = 0; e < 8; ++e) {
        const int kl = g * 8 + e;
        f3f[e] = (f16)((r == 0 && kl < 15) ? Wf3[kl] : 0.f);
    }
    f16x8 vf[2][2];                  // Wv: es(60) -> 30
    #pragma unroll
    for (int kt = 0; kt < 2; ++kt)
        #pragma unroll
        for (int nt = 0; nt < 2; ++nt) {
            const int j = nt * 16 + r;
            f16x8 w;
            #pragma unroll
            for (int e = 0; e < 8; ++e) {
                const int kl = kt * 32 + g * 8 + e;
                w[e] = (f16)((j < 30 && kl < 60) ? Wv[j * 60 + kl] : 0.f);
            }
            vf[kt][nt] = w;
        }

    // ---- biases (D-layout: depend on lane's col only)
    float bl[8], bgv[2], bf1v[2], wf1se[2];
    #pragma unroll
    for (int t = 0; t < 8; ++t) {
        const int gate = t >> 1, j = (t & 1) * 16 + r;
        bl[t] = (j < 30) ? bih[gate * 30 + j] + bhh[gate * 30 + j] : 0.f;
    }
    #pragma unroll
    for (int nt = 0; nt < 2; ++nt) {
        const int j = nt * 16 + r;
        bgv[nt]   = (j < 30) ? bg[j]  : 0.f;
        bf1v[nt]  = (j < 30) ? bf1[j] : 0.f;
        wf1se[nt] = (j < 30) ? Wf1[j * 31 + 30] : 0.f;
    }
    const float bf2v = (r < 15) ? bf2[r] : 0.f;
    const float bf3v = bf3[0];

    // ---- write es (scaled) into x16 rows 0..7 as f16
    {
        const int u0r = l / 15, u0q = l - u0r * 15;
        f16x4 h0 = {(f16)(a0x*esc), (f16)(a0y*esc), (f16)(a0z*esc), (f16)(a0w*esc)};
        *(f16x4*)&x16[u0r][u0q * 4] = h0;
        if (l < 56) {
            const int u1 = 64 + l, u1r = u1 / 15, u1q = u1 - u1r * 15;
            f16x4 h1 = {(f16)(a1x*esc), (f16)(a1y*esc), (f16)(a1z*esc), (f16)(a1w*esc)};
            *(f16x4*)&x16[u1r][u1q * 4] = h1;
        }
    }

    // ---- V = es @ Wv.T + bv  (softmax over singleton axis == 1 -> context = V)
    float VD[2][4];
    {
        const f16x8 ea0 = *(const f16x8*)((const char*)x16 + (size_t)r * 144 + g * 16);
        const f16x8 ea1 = *(const f16x8*)((const char*)x16 + (size_t)r * 144 + 64 + g * 16);
        f32x4 vd0 = MFMA16(ea0, vf[0][0], kz); vd0 = MFMA16(ea1, vf[1][0], vd0);
        f32x4 vd1 = MFMA16(ea0, vf[0][1], kz); vd1 = MFMA16(ea1, vf[1][1], vd1);
        const float bv0 = bv[r];                                     // nt0: j=r<16
        const float bv1 = (16 + r < 30) ? bv[16 + r] : 0.f;          // nt1
        #pragma unroll
        for (int q = 0; q < 4; ++q) { VD[0][q] = vd0[q] + bv0; VD[1][q] = vd1[q] + bv1; }
        // stage V through z1b to build the A-fragment (k = 0..31, pads zero)
        #pragma unroll
        for (int nt = 0; nt < 2; ++nt)
            #pragma unroll
            for (int q = 0; q < 4; ++q)
                z1b[4 * g + q][nt * 16 + r] = (f16)VD[nt][q];
    }
    const f16x8 va = *(const f16x8*)((const char*)z1b + (size_t)r * 64 + g * 16);

    // ---- h0 (D-layout regs + x16 h-region), rin0
    float hD[2][4];
    #pragma unroll
    for (int nt = 0; nt < 2; ++nt)
        #pragma unroll
        for (int q = 0; q < 4; ++q) {
            const int row = 4 * g + q, j = nt * 16 + r;
            hD[nt][q] = (row < 8 && j < 30) ? hidden[(size_t)(bw + row) * 30 + j] : 0.f;
            x16[row][34 + nt * 16 + r] = (f16)hD[nt][q];   // nt1 r>=14 -> scratch cols 64/65
        }
    if (l < 8) {
        const float* yp = y + (size_t)(bw + l) * 52;
        #pragma unroll
        for (int d = 0; d < 4; ++d) {
            float v = yp[d];
            x16[l][d] = (f16)((v == v) ? v : 0.f);
        }
    }

    // ---- 12-step recurrence (wave-private; no block barriers anywhere)
    float c[2][4] = {{0,0,0,0},{0,0,0,0}};
    #pragma unroll 1
    for (int i = 1; i <= 12; ++i) {
        const float se = (float)i * (1.f / 12.f);

        // A: gate = sig([h|V] @ Wg.T + bg); enh -> x16 cols 4..33
        // (xhg's cols 32,33 are stale enh[28,29] — zero-weighted in gf[0])
        {
            const f16x8 xhg = *(const f16x8*)((const char*)x16 + (size_t)r * 144 + 64 + g * 16);
            f32x4 gd0 = MFMA16(xhg, gf[0][0], kz); gd0 = MFMA16(va, gf[1][0], gd0);
            f32x4 gd1 = MFMA16(xhg, gf[0][1], kz); gd1 = MFMA16(va, gf[1][1], gd1);
            #pragma unroll
            for (int nt = 0; nt < 2; ++nt)
                #pragma unroll
                for (int q = 0; q < 4; ++q) {
                    const float a  = (nt ? gd1[q] : gd0[q]) + bgv[nt];
                    const float gt = fast_sig(a);
                    const float enh = gt * hD[nt][q] + (1.f - gt) * VD[nt][q];
                    const int j = nt * 16 + r;
                    if (j < 30) x16[4 * g + q][4 + j] = (f16)enh;
                }
        }

        // B: LSTM. BOTH A-tiles reloaded AFTER section A's enh stores —
        // cols 32,33 of tile 1 are enh[28,29] and must be fresh (r5 bug).
        {
            const f16x8 xa0 = *(const f16x8*)((const char*)x16 + (size_t)r * 144 + g * 16);
            const f16x8 xa1 = *(const f16x8*)((const char*)x16 + (size_t)r * 144 + 64 + g * 16);
            f32x4 ld[8];
            #pragma unroll
            for (int t = 0; t < 8; ++t) {
                ld[t] = MFMA16(xa0, lf[0][t], kz);
                ld[t] = MFMA16(xa1, lf[1][t], ld[t]);
            }
            #pragma unroll
            for (int jh = 0; jh < 2; ++jh)
                #pragma unroll
                for (int q = 0; q < 4; ++q) {
                    const float ii = fast_sig (ld[0 + jh][q] + bl[0 + jh]);
                    const float ff = fast_sig (ld[2 + jh][q] + bl[2 + jh]);
                    const float gg = fast_tanh(ld[4 + jh][q] + bl[4 + jh]);
                    const float oo = fast_sig (ld[6 + jh][q] + bl[6 + jh]);
                    const float cn = ff * c[jh][q] + ii * gg;
                    c[jh][q] = cn;
                    const float hn = oo * fast_tanh(cn);
                    hD[jh][q] = hn;
                    x16[4 * g + q][34 + jh * 16 + r] = (f16)hn;  // jh1 r>=14 -> scratch
                }
        }

        // C: z1 = relu([h_new|se] @ Wf1.T + bf1)   (se folded into dynamic bias)
        {
            const f16x8 hn = *(const f16x8*)((const char*)x16 + (size_t)r * 144 + 64 + g * 16);
            f32x4 d0 = MFMA16(hn, f1f[0], kz);
            f32x4 d1 = MFMA16(hn, f1f[1], kz);
            #pragma unroll
            for (int nt = 0; nt < 2; ++nt)
                #pragma unroll
                for (int q = 0; q < 4; ++q) {
                    const float z = fmaxf((nt ? d1[q] : d0[q]) + bf1v[nt] + se * wf1se[nt], 0.f);
                    z1b[4 * g + q][nt * 16 + r] = (f16)z;
                }
        }

        // D: z2 = relu(z1 @ Wf2.T + bf2) -> z1b cols 0..15
        {
            const f16x8 z1a = *(const f16x8*)((const char*)z1b + (size_t)r * 64 + g * 16);
            f32x4 d = MFMA16(z1a, f2f, kz);
            #pragma unroll
            for (int q = 0; q < 4; ++q)
                z1b[4 * g + q][r] = (f16)fmaxf(d[q] + bf2v, 0.f);
        }

        // E: out = z2 @ Wf3.T + bf3 (stale z1 cols 16..31 killed by zero weights)
        {
            const f16x8 z2a = *(const f16x8*)((const char*)z1b + (size_t)r * 64 + g * 16);
            f32x4 od = MFMA16(z2a, f3f, kz);
            if (r == 0 && g < 2) {
                #pragma unroll
                for (int q = 0; q < 4; ++q) {
                    const float o = od[q] + bf3v;
                    out[(size_t)(i - 1) * NB + bw + 4 * g + q] = o;
                    x16[4 * g + q][3] = (f16)o;           // rin[3] = out
                }
            }
            if (l < 8) {                                   // rin[0..2] = y[:, i, 1:4]
                const float* yp = y + (size_t)(bw + l) * 52 + (size_t)i * 4;
                x16[l][0] = (f16)yp[1];
                x16[l][1] = (f16)yp[2];
                x16[l][2] = (f16)yp[3];
            }
        }
    }
}

extern "C" void kernel_launch(void* const* d_in, const int* in_sizes, int n_in,
                              void* d_out, int out_size, void* d_ws, size_t ws_size,
                              hipStream_t stream) {
    (void)in_sizes; (void)n_in; (void)out_size;
    // 0 batch_ids, 1 y, 2 encoder_outputs, 3 hidden, 4 Wq, 5 bq, 6 Wk, 7 bk,
    // 8 Wv, 9 bv, 10 Wsa1, 11 bsa1, 12 Wsa2, 13 bsa2, 14 Wg, 15 bg,
    // 16 Wf1, 17 bf1, 18 Wf2, 19 bf2, 20 Wf3, 21 bf3, 22 W_ih, 23 b_ih,
    // 24 W_hh, 25 b_hh.  (Wq/bq/Wk/bk/Wsa* dead: softmax over size-1 axis == 1)
    const float* enc = (const float*)d_in[2];
    const size_t es_bytes = (size_t)NB * 60 * sizeof(float);
    float* es = (ws_size >= es_bytes) ? (float*)d_ws : nullptr;

    if (es) {   // split reduction: 3840 waves, BW-bound; decode reads 4MB from L2
        es_kernel<<<dim3(NB * 15 / 256), dim3(256), 0, stream>>>(enc, es);
    }
    decoder_kernel<<<dim3(NB / 8), dim3(64), 0, stream>>>(
        (const float*)d_in[1],  enc, es, (const float*)d_in[3],
        (const float*)d_in[8],  (const float*)d_in[9],
        (const float*)d_in[14], (const float*)d_in[15],
        (const float*)d_in[16], (const float*)d_in[17],
        (const float*)d_in[18], (const float*)d_in[19],
        (const float*)d_in[20], (const float*)d_in[21],
        (const float*)d_in[22], (const float*)d_in[23],
        (const float*)d_in[24], (const float*)d_in[25],
        (float*)d_out);
}

// Round 8
// 91.365 us; speedup vs baseline: 1.0367x; 1.0367x over previous
//
#include <hip/hip_runtime.h>
#include <math.h>

#define NB 16384
typedef _Float16 f16;
typedef _Float16 f16x8 __attribute__((ext_vector_type(8)));
typedef _Float16 f16x4 __attribute__((ext_vector_type(4)));
typedef float f32x4 __attribute__((ext_vector_type(4)));

__device__ __forceinline__ float fast_sig(float v)  { return __builtin_amdgcn_rcpf(1.0f + __expf(-v)); }
__device__ __forceinline__ float fast_tanh(float v) { return 1.0f - 2.0f * __builtin_amdgcn_rcpf(1.0f + __expf(2.0f * v)); }

#define MFMA16(A, B, C) __builtin_amdgcn_mfma_f32_16x16x32_f16(A, B, C, 0, 0, 0)

// ---------------- kernel 1: es = mean_L(enc), BW-bound, high occupancy ----------
__global__ __launch_bounds__(256) void es_kernel(
    const float* __restrict__ enc, float* __restrict__ es)
{
    const int u = blockIdx.x * 256 + threadIdx.x;    // float4 unit
    const float4* e4 = (const float4*)enc;
    float ax = 0.f, ay = 0.f, az = 0.f, aw = 0.f;
    #pragma unroll 8
    for (int L = 0; L < 48; ++L) {
        const float4 v = e4[(size_t)L * (NB * 15) + u];
        ax += v.x; ay += v.y; az += v.z; aw += v.w;
    }
    const float s = 1.f / 48.f;
    float4 r; r.x = ax * s; r.y = ay * s; r.z = az * s; r.w = aw * s;
    ((float4*)es)[u] = r;
}

// ---------------- kernel 2: decode, DUAL full 16-row tiles per wave -------------
// 32 batch rows / wave (tile tt=0: rows bw..bw+15, tt=1: bw+16..bw+31). All 16
// MFMA tile rows are real (no pad-row waste). The two tiles are independent
// dependency chains -> in-wave ILP hides LDS/transcendental latency.
// Weights persistent in VGPRs as f16 B-fragments, shared by both tiles.
// x16 row layout (72 halves, 144B stride): [0..3]=rin [4..33]=enh [34..63]=h [64..71]=scratch
__global__ __launch_bounds__(64, 1) void decoder_kernel(
    const float* __restrict__ y,      // [B,13,4]
    const float* __restrict__ enc,    // [48,B,60]
    const float* __restrict__ esrc,   // [B,60] premeaned (or null -> fused scan)
    const float* __restrict__ hidden, // [B,30]
    const float* __restrict__ Wv,  const float* __restrict__ bv,
    const float* __restrict__ Wg,  const float* __restrict__ bg,
    const float* __restrict__ Wf1, const float* __restrict__ bf1,
    const float* __restrict__ Wf2, const float* __restrict__ bf2,
    const float* __restrict__ Wf3, const float* __restrict__ bf3,
    const float* __restrict__ Wih, const float* __restrict__ bih,
    const float* __restrict__ Whh, const float* __restrict__ bhh,
    float* __restrict__ out)          // [12,B]
{
    __shared__ __align__(16) f16 x16[2][16][72];   // 2 x 2304 B
    __shared__ __align__(16) f16 z1b[2][16][32];   // 2 x 1024 B

    const int l = threadIdx.x;
    const int r = l & 15, g = l >> 4;        // A-row / D-col = r; k-block & D-row-group = g
    const int bw = blockIdx.x * 32;          // wave's first global batch row
    const f32x4 kz = {0.f, 0.f, 0.f, 0.f};

#define XB(tt) ((char*)x16 + (tt) * 2304)
#define ZB(tt) ((char*)z1b + (tt) * 1024)

    // ---- zero LDS
    #pragma unroll
    for (int d = 0; d < 18; ++d) ((unsigned*)x16)[d * 64 + l] = 0u;
    #pragma unroll
    for (int d = 0; d < 8; ++d)  ((unsigned*)z1b)[d * 64 + l] = 0u;

    // ---- phase 1: es for 32 rows -> x16 rows (read premeaned, or cold fallback)
    if (esrc) {
        const float4* s4 = (const float4*)esrc;
        #pragma unroll
        for (int tt = 0; tt < 2; ++tt) {
            const size_t base = (size_t)(bw + tt * 16) * 15;
            #pragma unroll
            for (int s = 0; s < 4; ++s) {
                const int u = s * 64 + l;                 // 240 units per tile
                if (s < 3 || l < 48) {
                    const float4 v = s4[base + u];
                    const int row = u / 15, q4 = u - row * 15;
                    f16x4 h = {(f16)v.x, (f16)v.y, (f16)v.z, (f16)v.w};
                    *(f16x4*)&x16[tt][row][q4 * 4] = h;
                }
            }
        }
    } else {   // cold correctness path: serial scan (ws too small)
        const float4* e4 = (const float4*)enc;
        const float s = 1.f / 48.f;
        for (int tt = 0; tt < 2; ++tt) {
            const size_t base = (size_t)(bw + tt * 16) * 15;
            #pragma unroll 1
            for (int s0 = 0; s0 < 4; ++s0) {
                const int u = s0 * 64 + l;
                if (u < 240) {
                    float ax = 0.f, ay = 0.f, az = 0.f, aw = 0.f;
                    for (int L = 0; L < 48; ++L) {
                        const float4 v = e4[(size_t)L * (NB * 15) + base + u];
                        ax += v.x; ay += v.y; az += v.z; aw += v.w;
                    }
                    const int row = u / 15, q4 = u - row * 15;
                    f16x4 h = {(f16)(ax*s), (f16)(ay*s), (f16)(az*s), (f16)(aw*s)};
                    *(f16x4*)&x16[tt][row][q4 * 4] = h;
                }
            }
        }
    }

    // ---- load weight B-fragments (f16, persistent in VGPRs, shared by tiles)
    // B-frag element e of lane l = W[k = kt*32 + g*8 + e][n = nt*16 + r]
    f16x8 lf[2][8];                  // LSTM; t = gate*2 + jh; k: 0..33 Wih, 34..63 Whh
    #pragma unroll
    for (int kt = 0; kt < 2; ++kt)
        #pragma unroll
        for (int t = 0; t < 8; ++t) {
            const int gate = t >> 1, j = (t & 1) * 16 + r;
            const int trow = gate * 30 + j;
            f16x8 w;
            #pragma unroll
            for (int e = 0; e < 8; ++e) {
                const int k = kt * 32 + g * 8 + e;
                float val = 0.f;
                if (j < 30) val = (k < 34) ? Wih[trow * 34 + k] : Whh[trow * 30 + (k - 34)];
                w[e] = (f16)val;
            }
            lf[kt][t] = w;
        }
    f16x8 gf[2][2];                  // gate; kt0 over x16 cols 32..63 (kl>=2 -> h), kt1 over V
    #pragma unroll
    for (int nt = 0; nt < 2; ++nt) {
        const int j = nt * 16 + r;
        f16x8 w0, w1;
        #pragma unroll
        for (int e = 0; e < 8; ++e) {
            const int kl = g * 8 + e;
            w0[e] = (f16)((j < 30 && kl >= 2) ? Wg[j * 60 + (kl - 2)] : 0.f);
            w1[e] = (f16)((j < 30 && kl < 30) ? Wg[j * 60 + 30 + kl] : 0.f);
        }
        gf[0][nt] = w0; gf[1][nt] = w1;
    }
    f16x8 f1f[2];                    // fc1 over x16 cols 32..63 (kl>=2 -> h_new); se via bias
    #pragma unroll
    for (int nt = 0; nt < 2; ++nt) {
        const int j = nt * 16 + r;
        f16x8 w;
        #pragma unroll
        for (int e = 0; e < 8; ++e) {
            const int kl = g * 8 + e;
            w[e] = (f16)((j < 30 && kl >= 2) ? Wf1[j * 31 + (kl - 2)] : 0.f);
        }
        f1f[nt] = w;
    }
    f16x8 f2f;                       // fc2: z1(30) -> 15
    #pragma unroll
    for (int e = 0; e < 8; ++e) {
        const int kl = g * 8 + e;
        f2f[e] = (f16)((r < 15 && kl < 30) ? Wf2[r * 30 + kl] : 0.f);
    }
    f16x8 f3f;                       // fc3: z2(15) -> 1 (col 0 only)
    #pragma unroll
    for (int e = 0; e < 8; ++e) {
        const int kl = g * 8 + e;
        f3f[e] = (f16)((r == 0 && kl < 15) ? Wf3[kl] : 0.f);
    }
    f16x8 vf[2][2];                  // Wv: es(60) -> 30
    #pragma unroll
    for (int kt = 0; kt < 2; ++kt)
        #pragma unroll
        for (int nt = 0; nt < 2; ++nt) {
            const int j = nt * 16 + r;
            f16x8 w;
            #pragma unroll
            for (int e = 0; e < 8; ++e) {
                const int kl = kt * 32 + g * 8 + e;
                w[e] = (f16)((j < 30 && kl < 60) ? Wv[j * 60 + kl] : 0.f);
            }
            vf[kt][nt] = w;
        }

    // ---- biases (D-layout: depend on lane's col only; shared by tiles)
    float bl[8], bgv[2], bf1v[2], wf1se[2];
    #pragma unroll
    for (int t = 0; t < 8; ++t) {
        const int gate = t >> 1, j = (t & 1) * 16 + r;
        bl[t] = (j < 30) ? bih[gate * 30 + j] + bhh[gate * 30 + j] : 0.f;
    }
    #pragma unroll
    for (int nt = 0; nt < 2; ++nt) {
        const int j = nt * 16 + r;
        bgv[nt]   = (j < 30) ? bg[j]  : 0.f;
        bf1v[nt]  = (j < 30) ? bf1[j] : 0.f;
        wf1se[nt] = (j < 30) ? Wf1[j * 31 + 30] : 0.f;
    }
    const float bf2v = (r < 15) ? bf2[r] : 0.f;
    const float bf3v = bf3[0];
    const float bv0  = bv[r];
    const float bv1  = (16 + r < 30) ? bv[16 + r] : 0.f;

    // ---- V = es @ Wv.T + bv per tile (softmax over singleton axis == 1)
    float VD[2][2][4];
    #pragma unroll
    for (int tt = 0; tt < 2; ++tt) {
        const f16x8 ea0 = *(const f16x8*)(XB(tt) + (size_t)r * 144 + g * 16);
        const f16x8 ea1 = *(const f16x8*)(XB(tt) + (size_t)r * 144 + 64 + g * 16);
        f32x4 vd0 = MFMA16(ea0, vf[0][0], kz); vd0 = MFMA16(ea1, vf[1][0], vd0);
        f32x4 vd1 = MFMA16(ea0, vf[0][1], kz); vd1 = MFMA16(ea1, vf[1][1], vd1);
        #pragma unroll
        for (int q = 0; q < 4; ++q) { VD[tt][0][q] = vd0[q] + bv0; VD[tt][1][q] = vd1[q] + bv1; }
        #pragma unroll
        for (int nt = 0; nt < 2; ++nt)
            #pragma unroll
            for (int q = 0; q < 4; ++q)
                z1b[tt][4 * g + q][nt * 16 + r] = (f16)VD[tt][nt][q];   // stage V for A-frag
    }
    f16x8 va[2];
    #pragma unroll
    for (int tt = 0; tt < 2; ++tt)
        va[tt] = *(const f16x8*)(ZB(tt) + (size_t)r * 64 + g * 16);

    // ---- h0 (D-layout regs + x16 h-region), rin0
    float hD[2][2][4];
    #pragma unroll
    for (int tt = 0; tt < 2; ++tt)
        #pragma unroll
        for (int nt = 0; nt < 2; ++nt)
            #pragma unroll
            for (int q = 0; q < 4; ++q) {
                const int row = 4 * g + q, j = nt * 16 + r;
                hD[tt][nt][q] = (j < 30) ? hidden[(size_t)(bw + tt * 16 + row) * 30 + j] : 0.f;
                x16[tt][row][34 + nt * 16 + r] = (f16)hD[tt][nt][q];  // nt1 r>=14 -> scratch
            }
    if (l < 32) {    // rin0 = nan_to_num(y[:,0,:]); global row = bw + l
        const float* yp = y + (size_t)(bw + l) * 52;
        #pragma unroll
        for (int d = 0; d < 4; ++d) {
            float v = yp[d];
            x16[l >> 4][l & 15][d] = (f16)((v == v) ? v : 0.f);
        }
    }

    // ---- 12-step recurrence (wave-private; dual independent chains)
    float c[2][2][4] = {};
    #pragma unroll 1
    for (int i = 1; i <= 12; ++i) {
        const float se = (float)i * (1.f / 12.f);

        // A: gate = sig([h|V] @ Wg.T + bg); enh -> x16 cols 4..33
        // (cols 32,33 stale enh[28,29] are zero-weighted in gf[0])
        #pragma unroll
        for (int tt = 0; tt < 2; ++tt) {
            const f16x8 xhg = *(const f16x8*)(XB(tt) + (size_t)r * 144 + 64 + g * 16);
            f32x4 gd0 = MFMA16(xhg, gf[0][0], kz); gd0 = MFMA16(va[tt], gf[1][0], gd0);
            f32x4 gd1 = MFMA16(xhg, gf[0][1], kz); gd1 = MFMA16(va[tt], gf[1][1], gd1);
            #pragma unroll
            for (int nt = 0; nt < 2; ++nt)
                #pragma unroll
                for (int q = 0; q < 4; ++q) {
                    const float a  = (nt ? gd1[q] : gd0[q]) + bgv[nt];
                    const float gt = fast_sig(a);
                    const float enh = gt * hD[tt][nt][q] + (1.f - gt) * VD[tt][nt][q];
                    const int j = nt * 16 + r;
                    if (j < 30) x16[tt][4 * g + q][4 + j] = (f16)enh;
                }
        }
        __builtin_amdgcn_wave_barrier();

        // B: LSTM. A-tiles reloaded AFTER A's enh stores (r5 bug lesson).
        #pragma unroll
        for (int tt = 0; tt < 2; ++tt) {
            const f16x8 xa0 = *(const f16x8*)(XB(tt) + (size_t)r * 144 + g * 16);
            const f16x8 xa1 = *(const f16x8*)(XB(tt) + (size_t)r * 144 + 64 + g * 16);
            f32x4 ld[8];
            #pragma unroll
            for (int t = 0; t < 8; ++t) {
                ld[t] = MFMA16(xa0, lf[0][t], kz);
                ld[t] = MFMA16(xa1, lf[1][t], ld[t]);
            }
            #pragma unroll
            for (int jh = 0; jh < 2; ++jh)
                #pragma unroll
                for (int q = 0; q < 4; ++q) {
                    const float ii = fast_sig (ld[0 + jh][q] + bl[0 + jh]);
                    const float ff = fast_sig (ld[2 + jh][q] + bl[2 + jh]);
                    const float gg = fast_tanh(ld[4 + jh][q] + bl[4 + jh]);
                    const float oo = fast_sig (ld[6 + jh][q] + bl[6 + jh]);
                    const float cn = ff * c[tt][jh][q] + ii * gg;
                    c[tt][jh][q] = cn;
                    const float hn = oo * fast_tanh(cn);
                    hD[tt][jh][q] = hn;
                    x16[tt][4 * g + q][34 + jh * 16 + r] = (f16)hn;   // jh1 r>=14 -> scratch
                }
        }
        __builtin_amdgcn_wave_barrier();

        // prefetch next rin's y components (consumed in E)
        float py1 = 0, py2 = 0, py3 = 0;
        if (l < 32) {
            const float* yp = y + (size_t)(bw + l) * 52 + (size_t)i * 4;
            py1 = yp[1]; py2 = yp[2]; py3 = yp[3];
        }

        // C: z1 = relu([h_new|se] @ Wf1.T + bf1)  (se folded into dynamic bias)
        #pragma unroll
        for (int tt = 0; tt < 2; ++tt) {
            const f16x8 hn = *(const f16x8*)(XB(tt) + (size_t)r * 144 + 64 + g * 16);
            f32x4 d0 = MFMA16(hn, f1f[0], kz);
            f32x4 d1 = MFMA16(hn, f1f[1], kz);
            #pragma unroll
            for (int nt = 0; nt < 2; ++nt)
                #pragma unroll
                for (int q = 0; q < 4; ++q) {
                    const float z = fmaxf((nt ? d1[q] : d0[q]) + bf1v[nt] + se * wf1se[nt], 0.f);
                    z1b[tt][4 * g + q][nt * 16 + r] = (f16)z;
                }
        }
        __builtin_amdgcn_wave_barrier();

        // D: z2 = relu(z1 @ Wf2.T + bf2) -> z1b cols 0..15
        #pragma unroll
        for (int tt = 0; tt < 2; ++tt) {
            const f16x8 z1a = *(const f16x8*)(ZB(tt) + (size_t)r * 64 + g * 16);
            f32x4 d = MFMA16(z1a, f2f, kz);
            #pragma unroll
            for (int q = 0; q < 4; ++q)
                z1b[tt][4 * g + q][r] = (f16)fmaxf(d[q] + bf2v, 0.f);
        }
        __builtin_amdgcn_wave_barrier();

        // E: out = z2 @ Wf3.T + bf3 (stale z1 cols 16..31 killed by zero weights)
        #pragma unroll
        for (int tt = 0; tt < 2; ++tt) {
            const f16x8 z2a = *(const f16x8*)(ZB(tt) + (size_t)r * 64 + g * 16);
            f32x4 od = MFMA16(z2a, f3f, kz);
            if (r == 0) {
                #pragma unroll
                for (int q = 0; q < 4; ++q) {
                    const float o = od[q] + bf3v;
                    out[(size_t)(i - 1) * NB + bw + tt * 16 + 4 * g + q] = o;
                    x16[tt][4 * g + q][3] = (f16)o;       // rin[3] = out
                }
            }
        }
        if (l < 32) {                                      // rin[0..2] = y[:, i, 1:4]
            x16[l >> 4][l & 15][0] = (f16)py1;
            x16[l >> 4][l & 15][1] = (f16)py2;
            x16[l >> 4][l & 15][2] = (f16)py3;
        }
        __builtin_amdgcn_wave_barrier();
    }
#undef XB
#undef ZB
}

extern "C" void kernel_launch(void* const* d_in, const int* in_sizes, int n_in,
                              void* d_out, int out_size, void* d_ws, size_t ws_size,
                              hipStream_t stream) {
    (void)in_sizes; (void)n_in; (void)out_size;
    // 0 batch_ids, 1 y, 2 encoder_outputs, 3 hidden, 4 Wq, 5 bq, 6 Wk, 7 bk,
    // 8 Wv, 9 bv, 10 Wsa1, 11 bsa1, 12 Wsa2, 13 bsa2, 14 Wg, 15 bg,
    // 16 Wf1, 17 bf1, 18 Wf2, 19 bf2, 20 Wf3, 21 bf3, 22 W_ih, 23 b_ih,
    // 24 W_hh, 25 b_hh.  (Wq/bq/Wk/bk/Wsa* dead: softmax over size-1 axis == 1)
    const float* enc = (const float*)d_in[2];
    const size_t es_bytes = (size_t)NB * 60 * sizeof(float);
    float* es = (ws_size >= es_bytes) ? (float*)d_ws : nullptr;

    if (es) {   // split reduction: 3840 waves, BW-bound; decode reads 4MB from L2
        es_kernel<<<dim3(NB * 15 / 256), dim3(256), 0, stream>>>(enc, es);
    }
    decoder_kernel<<<dim3(NB / 32), dim3(64), 0, stream>>>(
        (const float*)d_in[1],  enc, es, (const float*)d_in[3],
        (const float*)d_in[8],  (const float*)d_in[9],
        (const float*)d_in[14], (const float*)d_in[15],
        (const float*)d_in[16], (const float*)d_in[17],
        (const float*)d_in[18], (const float*)d_in[19],
        (const float*)d_in[20], (const float*)d_in[21],
        (const float*)d_in[22], (const float*)d_in[23],
        (const float*)d_in[24], (const float*)d_in[25],
        (float*)d_out);
}